// Round 8
// baseline (806.605 us; speedup 1.0000x reference)
//
#include <hip/hip_runtime.h>

#define U_N 100000
#define I_N 200000
#define D   64
#define NNZ_UI 2000000
#define NNZ_SOC 1000000
#define LN_EPS 1e-5f
#define LSLOPE 0.01f
#define SCAN_CHUNK 1024
#define SEDGES 2048   // edges per hist/scatter block (MUST match between them)
#define NREP 8        // counter replicas

using short8 = __attribute__((ext_vector_type(8))) short;
using f32x4  = __attribute__((ext_vector_type(4))) float;

__device__ __forceinline__ float bf2f(unsigned short h) {
    return __uint_as_float((unsigned int)h << 16);
}
__device__ __forceinline__ unsigned short f2bf(float f) {   // RNE
    unsigned int u = __float_as_uint(f);
    return (unsigned short)((u + 0x7FFFu + ((u >> 16) & 1u)) >> 16);
}

// ---------------------------------------------------------------------------
__global__ void zero_i4(int4* __restrict__ p, int n4) {
    int i = blockIdx.x * blockDim.x + threadIdx.x;
    if (i < n4) p[i] = make_int4(0, 0, 0, 0);
}

__global__ void copy2_f4(const float4* __restrict__ src, float4* __restrict__ d1,
                         float4* __restrict__ d2, int n4) {
    int i = blockIdx.x * blockDim.x + threadIdx.x;
    if (i < n4) {
        float4 v = src[i];
        d1[i] = v;
        d2[i] = v;
    }
}

__global__ void wbf_k(const float* __restrict__ wa, const float* __restrict__ wb,
                      unsigned short* __restrict__ dst) {
    int i = blockIdx.x * blockDim.x + threadIdx.x;
    float v = (i < 8192) ? wa[i] : wb[i - 8192];
    dst[i] = f2bf(v);
}

// ---------------------------------------------------------------------------
// Replicated + partition-swept histogram. Block lb covers edges
// [lb*SEDGES,(lb+1)*SEDGES), replica (lb & 7) — identical map to scatter_lds.
// Rows staged in LDS; atomics issued window-by-window for line clustering.
struct HistArgs {
    const int* rows[3];
    int* cg[3];
    int nnz[3];
    int nrows[3];
    int span[3];
    int nparts[3];
    int base[4];
};
__global__ __launch_bounds__(256) void hist_m(HistArgs a) {
    __shared__ int lr[SEDGES];
    int b = blockIdx.x;
    int si = (b >= a.base[1]) + (b >= a.base[2]);
    int lb = b - a.base[si];
    int* c = a.cg[si] + (lb & (NREP - 1)) * a.nrows[si];
    const int base = lb * SEDGES;
    const int cnt  = min(SEDGES, a.nnz[si] - base);
    const int4* r4 = (const int4*)(a.rows[si] + base);
    for (int i = threadIdx.x; i < (cnt >> 2); i += 256)
        ((int4*)lr)[i] = r4[i];
    __syncthreads();
    const int span = a.span[si], nparts = a.nparts[si];
    int lo = 0;
    for (int p = 0; p < nparts; ++p, lo += span) {
        for (int k = threadIdx.x; k < cnt; k += 256) {
            int r = lr[k];
            if ((unsigned)(r - lo) < (unsigned)span)
                atomicAdd(&c[r], 1);
        }
    }
}

// merge: per row, replica counts -> row-local exclusive prefix; rp[r] = total
struct MrgArgs {
    int* cg[3];
    int* rp[3];
    int n[3];
    int base[4];
};
__global__ __launch_bounds__(256) void merge_k(MrgArgs a) {
    int b = blockIdx.x;
    int si = (b >= a.base[1]) + (b >= a.base[2]);
    int r = (b - a.base[si]) * 256 + threadIdx.x;
    int n = a.n[si];
    if (r >= n) return;
    int* cg = a.cg[si];
    int s = 0;
    #pragma unroll
    for (int g = 0; g < NREP; ++g) {
        int t = cg[g * n + r];
        cg[g * n + r] = s;
        s += t;
    }
    a.rp[si][r] = s;
}

// addback: cg[g][r] += rp[r] (row start) -> absolute segment starts
__global__ __launch_bounds__(256) void addback_k(MrgArgs a) {
    int b = blockIdx.x;
    int si = (b >= a.base[1]) + (b >= a.base[2]);
    int r = (b - a.base[si]) * 256 + threadIdx.x;
    int n = a.n[si];
    if (r >= n) return;
    int* cg = a.cg[si];
    int base = a.rp[si][r];
    #pragma unroll
    for (int g = 0; g < NREP; ++g) cg[g * n + r] += base;
}

// merged scans (over rp arrays; exclusive prefix -> row starts) --------------
struct ScanArgs {
    int* cnt[3];
    int n[3];
    int off[3];
    int nb[3];
    int base[4];
};

__global__ __launch_bounds__(256) void scan_p1(ScanArgs a, int* __restrict__ bsum) {
    int b = blockIdx.x;
    int si = (b >= a.base[1]) + (b >= a.base[2]);
    int lb = b - a.base[si];
    const int* cnt = a.cnt[si];
    int n = a.n[si];
    int bs = lb * SCAN_CHUNK + threadIdx.x * 4;
    int s = 0;
    #pragma unroll
    for (int q = 0; q < 4; ++q) {
        int idx = bs + q;
        if (idx < n) s += cnt[idx];
    }
    #pragma unroll
    for (int m = 1; m < 64; m <<= 1) s += __shfl_xor(s, m, 64);
    __shared__ int ws[4];
    if ((threadIdx.x & 63) == 0) ws[threadIdx.x >> 6] = s;
    __syncthreads();
    if (threadIdx.x == 0) bsum[a.off[si] + lb] = ws[0] + ws[1] + ws[2] + ws[3];
}

__global__ __launch_bounds__(256) void scan_p2(ScanArgs a, int* __restrict__ bsum) {
    int si = blockIdx.x;
    int nb = a.nb[si];
    int* bp = bsum + a.off[si];
    int t = threadIdx.x;
    int v = (t < nb) ? bp[t] : 0;
    int lane = t & 63, w = t >> 6;
    int x = v;
    #pragma unroll
    for (int m = 1; m < 64; m <<= 1) {
        int y = __shfl_up(x, m, 64);
        if (lane >= m) x += y;
    }
    __shared__ int wtot[4];
    if (lane == 63) wtot[w] = x;
    __syncthreads();
    int off = 0;
    for (int i = 0; i < w; ++i) off += wtot[i];
    if (t < nb) bp[t] = (x + off) - v;
}

__global__ __launch_bounds__(256) void scan_p3(ScanArgs a, const int* __restrict__ bsum) {
    int b = blockIdx.x;
    int si = (b >= a.base[1]) + (b >= a.base[2]);
    int lb = b - a.base[si];
    int* cnt = a.cnt[si];
    int n = a.n[si];
    int bs = lb * SCAN_CHUNK + threadIdx.x * 4;
    int v[4];
    int s = 0;
    #pragma unroll
    for (int q = 0; q < 4; ++q) {
        int idx = bs + q;
        v[q] = (idx < n) ? cnt[idx] : 0;
        s += v[q];
    }
    int lane = threadIdx.x & 63, w = threadIdx.x >> 6;
    int x = s;
    #pragma unroll
    for (int m = 1; m < 64; m <<= 1) {
        int y = __shfl_up(x, m, 64);
        if (lane >= m) x += y;
    }
    __shared__ int wtot[4];
    if (lane == 63) wtot[w] = x;
    __syncthreads();
    int off = 0;
    for (int i = 0; i < w; ++i) off += wtot[i];
    int run = bsum[a.off[si] + lb] + (x - s) + off;
    #pragma unroll
    for (int q = 0; q < 4; ++q) {
        int idx = bs + q;
        int t = v[q];
        if (idx < n) cnt[idx] = run;
        run += t;
    }
}

// ---------------------------------------------------------------------------
// LDS-staged partitioned scatter; block lb covers edges [lb*SEDGES,...),
// replica (lb & 7) — identical to hist_m's mapping.
__global__ __launch_bounds__(256) void scatter_lds(
    const int* __restrict__ rows, const int* __restrict__ cols,
    const float* __restrict__ vals, int* __restrict__ cg, int nrows,
    int2* __restrict__ pairs, int nnz, int span, int nparts)
{
    __shared__ int   lr[SEDGES];
    __shared__ int   lc[SEDGES];
    __shared__ float lv[SEDGES];
    const int base = blockIdx.x * SEDGES;
    const int cnt  = min(SEDGES, nnz - base);
    int* ctr = cg + (blockIdx.x & (NREP - 1)) * nrows;
    for (int i = threadIdx.x; i < cnt; i += 256) {
        lr[i] = rows[base + i];
        lc[i] = cols[base + i];
        lv[i] = vals[base + i];
    }
    __syncthreads();
    int lo = 0;
    for (int p = 0; p < nparts; ++p, lo += span) {
        for (int k = threadIdx.x; k < cnt; k += 256) {
            int r = lr[k];
            if ((unsigned)(r - lo) < (unsigned)span) {
                int pos = atomicAdd(&ctr[r], 1);
                pairs[pos] = make_int2(lc[k], __float_as_int(lv[k]));
            }
        }
    }
}

// ---------------------------------------------------------------------------
// MFMA transform: dst_bf16[n,64] = src_f32[n,64] @ W^T
struct XfArgs {
    const float* src[3];
    const unsigned short* wbf[3];
    unsigned short* dst[3];
    int n[3];
    int base[4];
};
__global__ __launch_bounds__(256) void xform_mfma(XfArgs a) {
    int b = blockIdx.x;
    int si = (b >= a.base[1]) + (b >= a.base[2]);
    const float* src = a.src[si];
    const unsigned short* wb = a.wbf[si];
    unsigned short* dst = a.dst[si];
    const int n = a.n[si];

    const int lane = threadIdx.x & 63;
    const int wv   = threadIdx.x >> 6;
    const int rbw  = (b - a.base[si]) * 64 + wv * 16;
    const int m = lane & 15, g = lane >> 4;

    f32x4 acc0 = {0.f, 0.f, 0.f, 0.f};
    f32x4 acc1 = acc0, acc2 = acc0, acc3 = acc0;

    const int arow = min(rbw + m, n - 1);
    const float* xp = src + (size_t)arow * D + g * 8;
    const unsigned short* wp0 = wb + (size_t)m * D + g * 8;

    #pragma unroll
    for (int t = 0; t < 2; ++t) {
        float4 a0 = *(const float4*)(xp + t * 32);
        float4 a1 = *(const float4*)(xp + t * 32 + 4);
        short8 af;
        af[0] = (short)f2bf(a0.x); af[1] = (short)f2bf(a0.y);
        af[2] = (short)f2bf(a0.z); af[3] = (short)f2bf(a0.w);
        af[4] = (short)f2bf(a1.x); af[5] = (short)f2bf(a1.y);
        af[6] = (short)f2bf(a1.z); af[7] = (short)f2bf(a1.w);
        const unsigned short* wp = wp0 + t * 32;
        short8 b0 = *(const short8*)(wp);
        short8 b1 = *(const short8*)(wp + 16 * D);
        short8 b2 = *(const short8*)(wp + 32 * D);
        short8 b3 = *(const short8*)(wp + 48 * D);
        acc0 = __builtin_amdgcn_mfma_f32_16x16x32_bf16(af, b0, acc0, 0, 0, 0);
        acc1 = __builtin_amdgcn_mfma_f32_16x16x32_bf16(af, b1, acc1, 0, 0, 0);
        acc2 = __builtin_amdgcn_mfma_f32_16x16x32_bf16(af, b2, acc2, 0, 0, 0);
        acc3 = __builtin_amdgcn_mfma_f32_16x16x32_bf16(af, b3, acc3, 0, 0, 0);
    }

    #pragma unroll
    for (int reg = 0; reg < 4; ++reg) {
        int orow = rbw + g * 4 + reg;
        if (orow < n) {
            size_t o = (size_t)orow * D + m;
            dst[o]      = f2bf(acc0[reg]);
            dst[o + 16] = f2bf(acc1[reg]);
            dst[o + 32] = f2bf(acc2[reg]);
            dst[o + 48] = f2bf(acc3[reg]);
        }
    }
}

// ---------------------------------------------------------------------------
// Light SpMM + epilogue. rp holds row STARTS; end = (row==n-1)?nnz:rp[row+1].
struct SpArgs {
    const int* rptr[3];
    const int2* pairs[3];
    const unsigned short* y[3];
    const float* cur[3];
    const float* bias[3];
    const float* gamma[3];
    const float* beta[3];
    float* dst[3];
    int n[3];
    int nnzc[3];
    int base[4];
};
__global__ __launch_bounds__(256) void spmm_ln(SpArgs a) {
    int b = blockIdx.x;
    int si = (b >= a.base[1]) + (b >= a.base[2]);
    const int* rptr = a.rptr[si];
    const int2* pairs = a.pairs[si];
    const unsigned short* y = a.y[si];

    const int lane = threadIdx.x & 63;
    const int wv   = threadIdx.x >> 6;
    const int r = lane >> 4, sub = lane & 15;
    const int row = (b - a.base[si]) * 16 + wv * 4 + r;

    const int start = rptr[row];
    const int end   = (row == a.n[si] - 1) ? a.nnzc[si] : rptr[row + 1];

    float4 acc  = make_float4(0.f, 0.f, 0.f, 0.f);
    float4 acc2 = make_float4(0.f, 0.f, 0.f, 0.f);
    int e = start;
    for (; e + 4 <= end; e += 4) {
        int2 p0 = pairs[e];
        int2 p1 = pairs[e + 1];
        int2 p2 = pairs[e + 2];
        int2 p3 = pairs[e + 3];
        float v0 = __int_as_float(p0.y);
        float v1 = __int_as_float(p1.y);
        float v2 = __int_as_float(p2.y);
        float v3 = __int_as_float(p3.y);
        ushort4 q0 = *(const ushort4*)(y + (size_t)p0.x * D + sub * 4);
        ushort4 q1 = *(const ushort4*)(y + (size_t)p1.x * D + sub * 4);
        ushort4 q2 = *(const ushort4*)(y + (size_t)p2.x * D + sub * 4);
        ushort4 q3 = *(const ushort4*)(y + (size_t)p3.x * D + sub * 4);
        acc.x  += v0 * bf2f(q0.x); acc.y  += v0 * bf2f(q0.y);
        acc.z  += v0 * bf2f(q0.z); acc.w  += v0 * bf2f(q0.w);
        acc2.x += v1 * bf2f(q1.x); acc2.y += v1 * bf2f(q1.y);
        acc2.z += v1 * bf2f(q1.z); acc2.w += v1 * bf2f(q1.w);
        acc.x  += v2 * bf2f(q2.x); acc.y  += v2 * bf2f(q2.y);
        acc.z  += v2 * bf2f(q2.z); acc.w  += v2 * bf2f(q2.w);
        acc2.x += v3 * bf2f(q3.x); acc2.y += v3 * bf2f(q3.y);
        acc2.z += v3 * bf2f(q3.z); acc2.w += v3 * bf2f(q3.w);
    }
    for (; e < end; ++e) {
        int2 p0 = pairs[e];
        float v0 = __int_as_float(p0.y);
        ushort4 q0 = *(const ushort4*)(y + (size_t)p0.x * D + sub * 4);
        acc.x += v0 * bf2f(q0.x); acc.y += v0 * bf2f(q0.y);
        acc.z += v0 * bf2f(q0.z); acc.w += v0 * bf2f(q0.w);
    }
    acc.x += acc2.x; acc.y += acc2.y; acc.z += acc2.z; acc.w += acc2.w;

    float4 bi = *(const float4*)(a.bias[si] + sub * 4);
    float4 h;
    h.x = acc.x + bi.x; h.y = acc.y + bi.y; h.z = acc.z + bi.z; h.w = acc.w + bi.w;
    h.x = h.x > 0.f ? h.x : LSLOPE * h.x;
    h.y = h.y > 0.f ? h.y : LSLOPE * h.y;
    h.z = h.z > 0.f ? h.z : LSLOPE * h.z;
    h.w = h.w > 0.f ? h.w : LSLOPE * h.w;
    float4 cu = *(const float4*)(a.cur[si] + (size_t)row * D + sub * 4);
    float4 x;
    x.x = cu.x + h.x; x.y = cu.y + h.y; x.z = cu.z + h.z; x.w = cu.w + h.w;

    float s  = x.x + x.y + x.z + x.w;
    float s2 = x.x * x.x + x.y * x.y + x.z * x.z + x.w * x.w;
    #pragma unroll
    for (int m = 8; m >= 1; m >>= 1) {
        s  += __shfl_xor(s, m, 64);
        s2 += __shfl_xor(s2, m, 64);
    }
    float mean = s * (1.f / 64.f);
    float var  = s2 * (1.f / 64.f) - mean * mean;
    float rstd = rsqrtf(var + LN_EPS);

    float4 g4  = *(const float4*)(a.gamma[si] + sub * 4);
    float4 be4 = *(const float4*)(a.beta[si]  + sub * 4);
    float4 o;
    o.x = (x.x - mean) * rstd * g4.x + be4.x;
    o.y = (x.y - mean) * rstd * g4.y + be4.y;
    o.z = (x.z - mean) * rstd * g4.z + be4.z;
    o.w = (x.w - mean) * rstd * g4.w + be4.w;
    *(float4*)(a.dst[si] + (size_t)row * D + sub * 4) = o;
}

// ---------------------------------------------------------------------------
extern "C" void kernel_launch(void* const* d_in, const int* in_sizes, int n_in,
                              void* d_out, int out_size, void* d_ws, size_t ws_size,
                              hipStream_t stream)
{
    const float* user_emb = (const float*)d_in[0];
    const float* item_emb = (const float*)d_in[1];
    const int*   ui_rows  = (const int*)d_in[2];
    const int*   ui_cols  = (const int*)d_in[3];
    const float* ui_vals  = (const float*)d_in[4];
    const int*   soc_rows = (const int*)d_in[5];
    const int*   soc_cols = (const int*)d_in[6];
    const float* soc_vals = (const float*)d_in[7];
    const float* ui_W     = (const float*)d_in[8];
    const float* ui_b     = (const float*)d_in[9];
    const float* soc_W    = (const float*)d_in[10];
    const float* soc_b    = (const float*)d_in[11];
    const float* ln_ui_g  = (const float*)d_in[12];
    const float* ln_ui_b  = (const float*)d_in[13];
    const float* ln_soc_g = (const float*)d_in[14];
    const float* ln_soc_b = (const float*)d_in[15];

    float* out = (float*)d_out;
    const size_t UD = (size_t)U_N * D;
    const size_t ID = (size_t)I_N * D;

    float* o_ui0 = out;
    float* o_ui1 = out + UD;
    float* o_ui2 = out + 2 * UD;
    float* o_s0  = out + 3 * UD;
    float* o_s1  = out + 4 * UD;
    float* o_s2  = out + 5 * UD;
    float* o_ci  = out + 6 * UD;

    // workspace layout
    int2* pairs_ui  = (int2*)d_ws;                       // 2M
    int2* pairs_uiT = pairs_ui + NNZ_UI;                 // 2M
    int2* pairs_soc = pairs_uiT + NNZ_UI;                // 1M
    int*  rp_ui     = (int*)(pairs_soc + NNZ_SOC);       // U_N
    int*  rp_uiT    = rp_ui + U_N;                       // I_N
    int*  rp_soc    = rp_uiT + I_N;                      // U_N
    int*  bsum      = rp_soc + U_N;                      // 512
    unsigned short* wbf = (unsigned short*)(bsum + 512); // 16384
    unsigned short* Yi  = wbf + 16384;                   // I*D bf16
    unsigned short* Yu  = Yi + ID;                       // U*D bf16
    unsigned short* Ys  = Yu + UD;                       // U*D bf16
    // replica counters overlap Yi (12.8MB < 25.6MB); dead before T0 writes Yi
    int* cg_ui  = (int*)Yi;                              // NREP*U_N
    int* cg_uiT = cg_ui + NREP * U_N;                    // NREP*I_N
    int* cg_soc = cg_uiT + NREP * I_N;                   // NREP*U_N

    const unsigned short* wbfUI0 = wbf;
    const unsigned short* wbfUI1 = wbf + 4096;
    const unsigned short* wbfS0  = wbf + 8192;
    const unsigned short* wbfS1  = wbf + 12288;

    const int nthr = 256;

    // 1) zero replica counters
    {
        int ntot = NREP * (U_N + I_N + U_N);
        zero_i4<<<(ntot / 4 + nthr - 1) / nthr, nthr, 0, stream>>>((int4*)cg_ui, ntot / 4);
    }

    // 2) weights to bf16
    wbf_k<<<64, nthr, 0, stream>>>(ui_W, soc_W, wbf);

    // 3) replicated + partition-swept histogram (block = 2048 edges)
    {
        HistArgs ha;
        ha.rows[0] = ui_rows;  ha.cg[0] = cg_ui;  ha.nnz[0] = NNZ_UI;  ha.nrows[0] = U_N;
        ha.span[0] = (U_N + 15) / 16; ha.nparts[0] = 16;
        ha.rows[1] = ui_cols;  ha.cg[1] = cg_uiT; ha.nnz[1] = NNZ_UI;  ha.nrows[1] = I_N;
        ha.span[1] = (I_N + 15) / 16; ha.nparts[1] = 16;
        ha.rows[2] = soc_rows; ha.cg[2] = cg_soc; ha.nnz[2] = NNZ_SOC; ha.nrows[2] = U_N;
        ha.span[2] = (U_N + 7) / 8; ha.nparts[2] = 8;
        int g0 = (NNZ_UI  + SEDGES - 1) / SEDGES;   // 977
        int g1 = g0;
        int g2 = (NNZ_SOC + SEDGES - 1) / SEDGES;   // 489
        ha.base[0] = 0; ha.base[1] = g0; ha.base[2] = g0 + g1; ha.base[3] = g0 + g1 + g2;
        hist_m<<<ha.base[3], nthr, 0, stream>>>(ha);
    }

    // 4) merge replicas -> local prefixes + totals, scan totals, add back
    MrgArgs ma;
    {
        ma.cg[0] = cg_ui;  ma.rp[0] = rp_ui;  ma.n[0] = U_N;
        ma.cg[1] = cg_uiT; ma.rp[1] = rp_uiT; ma.n[1] = I_N;
        ma.cg[2] = cg_soc; ma.rp[2] = rp_soc; ma.n[2] = U_N;
        int g0 = (U_N + nthr - 1) / nthr, g1 = (I_N + nthr - 1) / nthr, g2 = g0;
        ma.base[0] = 0; ma.base[1] = g0; ma.base[2] = g0 + g1; ma.base[3] = g0 + g1 + g2;
        merge_k<<<ma.base[3], nthr, 0, stream>>>(ma);
    }
    {
        ScanArgs sa;
        sa.cnt[0] = rp_ui;  sa.n[0] = U_N;
        sa.cnt[1] = rp_uiT; sa.n[1] = I_N;
        sa.cnt[2] = rp_soc; sa.n[2] = U_N;
        int nb0 = (U_N + SCAN_CHUNK - 1) / SCAN_CHUNK;
        int nb1 = (I_N + SCAN_CHUNK - 1) / SCAN_CHUNK;
        int nb2 = nb0;
        sa.nb[0] = nb0; sa.nb[1] = nb1; sa.nb[2] = nb2;
        sa.off[0] = 0; sa.off[1] = nb0; sa.off[2] = nb0 + nb1;
        sa.base[0] = 0; sa.base[1] = nb0; sa.base[2] = nb0 + nb1; sa.base[3] = nb0 + nb1 + nb2;
        scan_p1<<<sa.base[3], nthr, 0, stream>>>(sa, bsum);
        scan_p2<<<3, nthr, 0, stream>>>(sa, bsum);
        scan_p3<<<sa.base[3], nthr, 0, stream>>>(sa, bsum);
    }
    addback_k<<<ma.base[3], nthr, 0, stream>>>(ma);

    // 5) LDS-staged partitioned scatters (replica counters; 3 dispatches)
    {
        int gb_ui  = (NNZ_UI  + SEDGES - 1) / SEDGES;
        int gb_soc = (NNZ_SOC + SEDGES - 1) / SEDGES;
        scatter_lds<<<gb_ui, nthr, 0, stream>>>(ui_rows, ui_cols, ui_vals,
                                                cg_ui, U_N, pairs_ui, NNZ_UI, (U_N + 15) / 16, 16);
        scatter_lds<<<gb_ui, nthr, 0, stream>>>(ui_cols, ui_rows, ui_vals,
                                                cg_uiT, I_N, pairs_uiT, NNZ_UI, (I_N + 15) / 16, 16);
        scatter_lds<<<gb_soc, nthr, 0, stream>>>(soc_rows, soc_cols, soc_vals,
                                                 cg_soc, U_N, pairs_soc, NNZ_SOC, (U_N + 7) / 8, 8);
    }

    // 6) copy user_emb to output slots
    copy2_f4<<<(int)(UD / 4 + nthr - 1) / nthr, nthr, 0, stream>>>(
        (const float4*)user_emb, (float4*)o_ui0, (float4*)o_s0, (int)(UD / 4));

    const int xb_i = (I_N + 63) / 64;
    const int xb_u = (U_N + 63) / 64;

    // 7) T0
    {
        XfArgs xa;
        xa.src[0] = item_emb; xa.wbf[0] = wbfUI0; xa.dst[0] = Yi; xa.n[0] = I_N;
        xa.src[1] = user_emb; xa.wbf[1] = wbfUI0; xa.dst[1] = Yu; xa.n[1] = U_N;
        xa.src[2] = user_emb; xa.wbf[2] = wbfS0;  xa.dst[2] = Ys; xa.n[2] = U_N;
        xa.base[0] = 0; xa.base[1] = xb_i; xa.base[2] = xb_i + xb_u; xa.base[3] = xb_i + 2 * xb_u;
        xform_mfma<<<xa.base[3], nthr, 0, stream>>>(xa);
    }

    // 8) spmm L0
    {
        SpArgs pa;
        pa.rptr[0] = rp_ui;  pa.pairs[0] = pairs_ui;  pa.y[0] = Yi; pa.cur[0] = user_emb;
        pa.bias[0] = ui_b;  pa.gamma[0] = ln_ui_g;  pa.beta[0] = ln_ui_b;  pa.dst[0] = o_ui1;
        pa.n[0] = U_N; pa.nnzc[0] = NNZ_UI;
        pa.rptr[1] = rp_uiT; pa.pairs[1] = pairs_uiT; pa.y[1] = Yu; pa.cur[1] = item_emb;
        pa.bias[1] = ui_b;  pa.gamma[1] = ln_ui_g;  pa.beta[1] = ln_ui_b;  pa.dst[1] = o_ci;
        pa.n[1] = I_N; pa.nnzc[1] = NNZ_UI;
        pa.rptr[2] = rp_soc; pa.pairs[2] = pairs_soc; pa.y[2] = Ys; pa.cur[2] = user_emb;
        pa.bias[2] = soc_b; pa.gamma[2] = ln_soc_g; pa.beta[2] = ln_soc_b; pa.dst[2] = o_s1;
        pa.n[2] = U_N; pa.nnzc[2] = NNZ_SOC;
        pa.base[0] = 0; pa.base[1] = U_N / 16; pa.base[2] = U_N / 16 + I_N / 16;
        pa.base[3] = 2 * (U_N / 16) + I_N / 16;
        spmm_ln<<<pa.base[3], nthr, 0, stream>>>(pa);
    }

    // 9) T1
    {
        XfArgs xa;
        xa.src[0] = o_ci;  xa.wbf[0] = wbfUI1; xa.dst[0] = Yi; xa.n[0] = I_N;
        xa.src[1] = o_ui1; xa.wbf[1] = wbfUI1; xa.dst[1] = Yu; xa.n[1] = U_N;
        xa.src[2] = o_s1;  xa.wbf[2] = wbfS1;  xa.dst[2] = Ys; xa.n[2] = U_N;
        xa.base[0] = 0; xa.base[1] = xb_i; xa.base[2] = xb_i + xb_u; xa.base[3] = xb_i + 2 * xb_u;
        xform_mfma<<<xa.base[3], nthr, 0, stream>>>(xa);
    }

    // 10) spmm L1
    {
        SpArgs pa;
        pa.rptr[0] = rp_ui;  pa.pairs[0] = pairs_ui;  pa.y[0] = Yi; pa.cur[0] = o_ui1;
        pa.bias[0] = ui_b + 64;  pa.gamma[0] = ln_ui_g + 64;  pa.beta[0] = ln_ui_b + 64;
        pa.dst[0] = o_ui2;
        pa.n[0] = U_N; pa.nnzc[0] = NNZ_UI;
        pa.rptr[1] = rp_uiT; pa.pairs[1] = pairs_uiT; pa.y[1] = Yu; pa.cur[1] = o_ci;
        pa.bias[1] = ui_b + 64;  pa.gamma[1] = ln_ui_g + 64;  pa.beta[1] = ln_ui_b + 64;
        pa.dst[1] = o_ci;   // in-place: row read then written by same thread
        pa.n[1] = I_N; pa.nnzc[1] = NNZ_UI;
        pa.rptr[2] = rp_soc; pa.pairs[2] = pairs_soc; pa.y[2] = Ys; pa.cur[2] = o_s1;
        pa.bias[2] = soc_b + 64; pa.gamma[2] = ln_soc_g + 64; pa.beta[2] = ln_soc_b + 64;
        pa.dst[2] = o_s2;
        pa.n[2] = U_N; pa.nnzc[2] = NNZ_SOC;
        pa.base[0] = 0; pa.base[1] = U_N / 16; pa.base[2] = U_N / 16 + I_N / 16;
        pa.base[3] = 2 * (U_N / 16) + I_N / 16;
        spmm_ln<<<pa.base[3], nthr, 0, stream>>>(pa);
    }
}

// Round 10
// 497.976 us; speedup vs baseline: 1.6198x; 1.6198x over previous
//
#include <hip/hip_runtime.h>

#define U_N 100000
#define I_N 200000
#define D   64
#define NNZ_UI 2000000
#define NNZ_SOC 1000000
#define LN_EPS 1e-5f
#define LSLOPE 0.01f
#define SCAN_CHUNK 1024
#define HCH 8192        // edges per bucket-count/scatter block
#define BSPAN 196       // rows per bucket
#define NB_UI 512       // 512*196 = 100352 >= 100000
#define NB_UIT 1024     // 1024*196 = 200704 >= 200000
#define NB_SOC 512
#define NBLK_UI 245     // ceil(2M/8192)
#define NBLK_SOC 123    // ceil(1M/8192)

using short8 = __attribute__((ext_vector_type(8))) short;
using f32x4  = __attribute__((ext_vector_type(4))) float;

__device__ __forceinline__ float bf2f(unsigned short h) {
    return __uint_as_float((unsigned int)h << 16);
}
__device__ __forceinline__ unsigned short f2bf(float f) {   // RNE
    unsigned int u = __float_as_uint(f);
    return (unsigned short)((u + 0x7FFFu + ((u >> 16) & 1u)) >> 16);
}

// ---------------------------------------------------------------------------
__global__ void copy2_f4(const float4* __restrict__ src, float4* __restrict__ d1,
                         float4* __restrict__ d2, int n4) {
    int i = blockIdx.x * blockDim.x + threadIdx.x;
    if (i < n4) {
        float4 v = src[i];
        d1[i] = v;
        d2[i] = v;
    }
}

__global__ void wbf_k(const float* __restrict__ wa, const float* __restrict__ wb,
                      unsigned short* __restrict__ dst) {
    int i = blockIdx.x * blockDim.x + threadIdx.x;
    float v = (i < 8192) ? wa[i] : wb[i - 8192];
    dst[i] = f2bf(v);
}

// ---------------------------------------------------------------------------
// Phase A: per-block LDS bucket histogram -> cnt[bucket][block] (plain stores)
struct BCArgs {
    const int4* rows4[3];
    int* cnt[3];
    int nnz[3];
    int nblk[3];
    int nbuck[3];
    int base[4];
};
__global__ __launch_bounds__(256) void bucket_cnt(BCArgs a) {
    __shared__ int lcnt[1024];
    int b = blockIdx.x;
    int si = (b >= a.base[1]) + (b >= a.base[2]);
    int lb = b - a.base[si];
    const int nbuck = a.nbuck[si];
    for (int i = threadIdx.x; i < nbuck; i += 256) lcnt[i] = 0;
    __syncthreads();
    const int be = lb * HCH;
    const int cnt_e = min(HCH, a.nnz[si] - be);
    const int4* r4 = a.rows4[si] + (be >> 2);
    for (int i = threadIdx.x; i < (cnt_e >> 2); i += 256) {
        int4 v = r4[i];
        atomicAdd(&lcnt[v.x / BSPAN], 1);
        atomicAdd(&lcnt[v.y / BSPAN], 1);
        atomicAdd(&lcnt[v.z / BSPAN], 1);
        atomicAdd(&lcnt[v.w / BSPAN], 1);
    }
    __syncthreads();
    int* cnt = a.cnt[si];
    const int nblk = a.nblk[si];
    for (int k = threadIdx.x; k < nbuck; k += 256) cnt[k * nblk + lb] = lcnt[k];
}

// merged 3-section scans (exclusive prefix over bucket-major count matrices) --
struct ScanArgs {
    int* cnt[3];
    int n[3];
    int off[3];
    int nb[3];
    int base[4];
};

__global__ __launch_bounds__(256) void scan_p1(ScanArgs a, int* __restrict__ bsum) {
    int b = blockIdx.x;
    int si = (b >= a.base[1]) + (b >= a.base[2]);
    int lb = b - a.base[si];
    const int* cnt = a.cnt[si];
    int n = a.n[si];
    int bs = lb * SCAN_CHUNK + threadIdx.x * 4;
    int s = 0;
    #pragma unroll
    for (int q = 0; q < 4; ++q) {
        int idx = bs + q;
        if (idx < n) s += cnt[idx];
    }
    #pragma unroll
    for (int m = 1; m < 64; m <<= 1) s += __shfl_xor(s, m, 64);
    __shared__ int ws[4];
    if ((threadIdx.x & 63) == 0) ws[threadIdx.x >> 6] = s;
    __syncthreads();
    if (threadIdx.x == 0) bsum[a.off[si] + lb] = ws[0] + ws[1] + ws[2] + ws[3];
}

__global__ __launch_bounds__(256) void scan_p2(ScanArgs a, int* __restrict__ bsum) {
    int si = blockIdx.x;
    int nb = a.nb[si];
    int* bp = bsum + a.off[si];
    int t = threadIdx.x;
    int v = (t < nb) ? bp[t] : 0;
    int lane = t & 63, w = t >> 6;
    int x = v;
    #pragma unroll
    for (int m = 1; m < 64; m <<= 1) {
        int y = __shfl_up(x, m, 64);
        if (lane >= m) x += y;
    }
    __shared__ int wtot[4];
    if (lane == 63) wtot[w] = x;
    __syncthreads();
    int off = 0;
    for (int i = 0; i < w; ++i) off += wtot[i];
    if (t < nb) bp[t] = (x + off) - v;
}

__global__ __launch_bounds__(256) void scan_p3(ScanArgs a, const int* __restrict__ bsum) {
    int b = blockIdx.x;
    int si = (b >= a.base[1]) + (b >= a.base[2]);
    int lb = b - a.base[si];
    int* cnt = a.cnt[si];
    int n = a.n[si];
    int bs = lb * SCAN_CHUNK + threadIdx.x * 4;
    int v[4];
    int s = 0;
    #pragma unroll
    for (int q = 0; q < 4; ++q) {
        int idx = bs + q;
        v[q] = (idx < n) ? cnt[idx] : 0;
        s += v[q];
    }
    int lane = threadIdx.x & 63, w = threadIdx.x >> 6;
    int x = s;
    #pragma unroll
    for (int m = 1; m < 64; m <<= 1) {
        int y = __shfl_up(x, m, 64);
        if (lane >= m) x += y;
    }
    __shared__ int wtot[4];
    if (lane == 63) wtot[w] = x;
    __syncthreads();
    int off = 0;
    for (int i = 0; i < w; ++i) off += wtot[i];
    int run = bsum[a.off[si] + lb] + (x - s) + off;
    #pragma unroll
    for (int q = 0; q < 4; ++q) {
        int idx = bs + q;
        int t = v[q];
        if (idx < n) cnt[idx] = run;
        run += t;
    }
}

// ---------------------------------------------------------------------------
// Phase C: write edges to bucket-grouped copy; positions = scanned (bucket,
// block) base + LDS-atomic rank. No global atomics. Packs localrow in bits
// 24..31 of x (col < 2^24, localrow < 196). NOTE: unpack with UNSIGNED shift.
struct BSArgs {
    const int* rows[3];
    const int* cols[3];
    const float* vals[3];
    const int* cofs[3];
    int2* bkt[3];
    int nnz[3];
    int nblk[3];
    int nbuck[3];
    int base[4];
};
__global__ __launch_bounds__(256) void bucket_scat(BSArgs a) {
    __shared__ int lofs[1024];
    int b = blockIdx.x;
    int si = (b >= a.base[1]) + (b >= a.base[2]);
    int lb = b - a.base[si];
    const int nbuck = a.nbuck[si];
    const int nblk = a.nblk[si];
    const int* cofs = a.cofs[si];
    for (int k = threadIdx.x; k < nbuck; k += 256) lofs[k] = cofs[k * nblk + lb];
    __syncthreads();
    const int be = lb * HCH;
    const int cnt_e = min(HCH, a.nnz[si] - be);
    const int4* r4 = (const int4*)(a.rows[si] + be);
    const int4* c4 = (const int4*)(a.cols[si] + be);
    const float4* v4 = (const float4*)(a.vals[si] + be);
    int2* bkt = a.bkt[si];
    for (int i = threadIdx.x; i < (cnt_e >> 2); i += 256) {
        int4 r = r4[i];
        int4 c = c4[i];
        float4 v = v4[i];
        int k0 = r.x / BSPAN; int p0 = atomicAdd(&lofs[k0], 1);
        bkt[p0] = make_int2((int)((unsigned)c.x | ((unsigned)(r.x - k0 * BSPAN) << 24)),
                            __float_as_int(v.x));
        int k1 = r.y / BSPAN; int p1 = atomicAdd(&lofs[k1], 1);
        bkt[p1] = make_int2((int)((unsigned)c.y | ((unsigned)(r.y - k1 * BSPAN) << 24)),
                            __float_as_int(v.y));
        int k2 = r.z / BSPAN; int p2 = atomicAdd(&lofs[k2], 1);
        bkt[p2] = make_int2((int)((unsigned)c.z | ((unsigned)(r.z - k2 * BSPAN) << 24)),
                            __float_as_int(v.z));
        int k3 = r.w / BSPAN; int p3 = atomicAdd(&lofs[k3], 1);
        bkt[p3] = make_int2((int)((unsigned)c.w | ((unsigned)(r.w - k3 * BSPAN) << 24)),
                            __float_as_int(v.w));
    }
}

// ---------------------------------------------------------------------------
// Phase D: one block per bucket. LDS row histogram -> block scan -> rp writes
// (coalesced) -> row-sorted pairs written within the bucket's window.
struct BDArgs {
    const int* cofs[3];
    const int2* bkt[3];
    int2* pairs[3];
    int* rp[3];
    int nnz[3];
    int nblk[3];
    int nbuck[3];
    int nrows[3];
    int base[4];
};
__global__ __launch_bounds__(256) void bucket_csr(BDArgs a) {
    __shared__ int lcnt[BSPAN];
    __shared__ int lrun[BSPAN];
    __shared__ int wt[4];
    int b = blockIdx.x;
    int si = (b >= a.base[1]) + (b >= a.base[2]);
    int k = b - a.base[si];
    const int nblk = a.nblk[si];
    const int* cofs = a.cofs[si];
    const int base_p = cofs[k * nblk];
    const int end_p = (k == a.nbuck[si] - 1) ? a.nnz[si] : cofs[(k + 1) * nblk];
    const int2* bkt = a.bkt[si];
    const int tid = threadIdx.x;
    if (tid < BSPAN) lcnt[tid] = 0;
    __syncthreads();
    for (int e = base_p + tid; e < end_p; e += 256)
        atomicAdd(&lcnt[(unsigned)bkt[e].x >> 24], 1);   // UNSIGNED shift!
    __syncthreads();
    // exclusive block scan of lcnt[0..BSPAN)
    int v = (tid < BSPAN) ? lcnt[tid] : 0;
    int lane = tid & 63, w = tid >> 6;
    int x = v;
    #pragma unroll
    for (int m = 1; m < 64; m <<= 1) {
        int y = __shfl_up(x, m, 64);
        if (lane >= m) x += y;
    }
    if (lane == 63) wt[w] = x;
    __syncthreads();
    int off = 0;
    for (int i = 0; i < w; ++i) off += wt[i];
    int excl = x + off - v;
    const int row0 = k * BSPAN;
    if (tid < BSPAN) {
        lrun[tid] = excl;
        if (row0 + tid < a.nrows[si]) a.rp[si][row0 + tid] = base_p + excl;
    }
    __syncthreads();
    int2* pairs = a.pairs[si];
    for (int e = base_p + tid; e < end_p; e += 256) {
        int2 q = bkt[e];
        int lr = (int)((unsigned)q.x >> 24);             // UNSIGNED shift!
        int pos = base_p + atomicAdd(&lrun[lr], 1);
        pairs[pos] = make_int2(q.x & 0xFFFFFF, q.y);
    }
}

// ---------------------------------------------------------------------------
// MFMA transform: dst_bf16[n,64] = src_f32[n,64] @ W^T
struct XfArgs {
    const float* src[3];
    const unsigned short* wbf[3];
    unsigned short* dst[3];
    int n[3];
    int base[4];
};
__global__ __launch_bounds__(256) void xform_mfma(XfArgs a) {
    int b = blockIdx.x;
    int si = (b >= a.base[1]) + (b >= a.base[2]);
    const float* src = a.src[si];
    const unsigned short* wb = a.wbf[si];
    unsigned short* dst = a.dst[si];
    const int n = a.n[si];

    const int lane = threadIdx.x & 63;
    const int wv   = threadIdx.x >> 6;
    const int rbw  = (b - a.base[si]) * 64 + wv * 16;
    const int m = lane & 15, g = lane >> 4;

    f32x4 acc0 = {0.f, 0.f, 0.f, 0.f};
    f32x4 acc1 = acc0, acc2 = acc0, acc3 = acc0;

    const int arow = min(rbw + m, n - 1);
    const float* xp = src + (size_t)arow * D + g * 8;
    const unsigned short* wp0 = wb + (size_t)m * D + g * 8;

    #pragma unroll
    for (int t = 0; t < 2; ++t) {
        float4 a0 = *(const float4*)(xp + t * 32);
        float4 a1 = *(const float4*)(xp + t * 32 + 4);
        short8 af;
        af[0] = (short)f2bf(a0.x); af[1] = (short)f2bf(a0.y);
        af[2] = (short)f2bf(a0.z); af[3] = (short)f2bf(a0.w);
        af[4] = (short)f2bf(a1.x); af[5] = (short)f2bf(a1.y);
        af[6] = (short)f2bf(a1.z); af[7] = (short)f2bf(a1.w);
        const unsigned short* wp = wp0 + t * 32;
        short8 b0 = *(const short8*)(wp);
        short8 b1 = *(const short8*)(wp + 16 * D);
        short8 b2 = *(const short8*)(wp + 32 * D);
        short8 b3 = *(const short8*)(wp + 48 * D);
        acc0 = __builtin_amdgcn_mfma_f32_16x16x32_bf16(af, b0, acc0, 0, 0, 0);
        acc1 = __builtin_amdgcn_mfma_f32_16x16x32_bf16(af, b1, acc1, 0, 0, 0);
        acc2 = __builtin_amdgcn_mfma_f32_16x16x32_bf16(af, b2, acc2, 0, 0, 0);
        acc3 = __builtin_amdgcn_mfma_f32_16x16x32_bf16(af, b3, acc3, 0, 0, 0);
    }

    #pragma unroll
    for (int reg = 0; reg < 4; ++reg) {
        int orow = rbw + g * 4 + reg;
        if (orow < n) {
            size_t o = (size_t)orow * D + m;
            dst[o]      = f2bf(acc0[reg]);
            dst[o + 16] = f2bf(acc1[reg]);
            dst[o + 32] = f2bf(acc2[reg]);
            dst[o + 48] = f2bf(acc3[reg]);
        }
    }
}

// ---------------------------------------------------------------------------
// Light SpMM + epilogue. rp holds row STARTS; end = (row==n-1)?nnz:rp[row+1].
struct SpArgs {
    const int* rptr[3];
    const int2* pairs[3];
    const unsigned short* y[3];
    const float* cur[3];
    const float* bias[3];
    const float* gamma[3];
    const float* beta[3];
    float* dst[3];
    int n[3];
    int nnzc[3];
    int base[4];
};
__global__ __launch_bounds__(256) void spmm_ln(SpArgs a) {
    int b = blockIdx.x;
    int si = (b >= a.base[1]) + (b >= a.base[2]);
    const int* rptr = a.rptr[si];
    const int2* pairs = a.pairs[si];
    const unsigned short* y = a.y[si];

    const int lane = threadIdx.x & 63;
    const int wv   = threadIdx.x >> 6;
    const int r = lane >> 4, sub = lane & 15;
    const int row = (b - a.base[si]) * 16 + wv * 4 + r;

    const int start = rptr[row];
    const int end   = (row == a.n[si] - 1) ? a.nnzc[si] : rptr[row + 1];

    float4 acc  = make_float4(0.f, 0.f, 0.f, 0.f);
    float4 acc2 = make_float4(0.f, 0.f, 0.f, 0.f);
    int e = start;
    for (; e + 4 <= end; e += 4) {
        int2 p0 = pairs[e];
        int2 p1 = pairs[e + 1];
        int2 p2 = pairs[e + 2];
        int2 p3 = pairs[e + 3];
        float v0 = __int_as_float(p0.y);
        float v1 = __int_as_float(p1.y);
        float v2 = __int_as_float(p2.y);
        float v3 = __int_as_float(p3.y);
        ushort4 q0 = *(const ushort4*)(y + (size_t)p0.x * D + sub * 4);
        ushort4 q1 = *(const ushort4*)(y + (size_t)p1.x * D + sub * 4);
        ushort4 q2 = *(const ushort4*)(y + (size_t)p2.x * D + sub * 4);
        ushort4 q3 = *(const ushort4*)(y + (size_t)p3.x * D + sub * 4);
        acc.x  += v0 * bf2f(q0.x); acc.y  += v0 * bf2f(q0.y);
        acc.z  += v0 * bf2f(q0.z); acc.w  += v0 * bf2f(q0.w);
        acc2.x += v1 * bf2f(q1.x); acc2.y += v1 * bf2f(q1.y);
        acc2.z += v1 * bf2f(q1.z); acc2.w += v1 * bf2f(q1.w);
        acc.x  += v2 * bf2f(q2.x); acc.y  += v2 * bf2f(q2.y);
        acc.z  += v2 * bf2f(q2.z); acc.w  += v2 * bf2f(q2.w);
        acc2.x += v3 * bf2f(q3.x); acc2.y += v3 * bf2f(q3.y);
        acc2.z += v3 * bf2f(q3.z); acc2.w += v3 * bf2f(q3.w);
    }
    for (; e < end; ++e) {
        int2 p0 = pairs[e];
        float v0 = __int_as_float(p0.y);
        ushort4 q0 = *(const ushort4*)(y + (size_t)p0.x * D + sub * 4);
        acc.x += v0 * bf2f(q0.x); acc.y += v0 * bf2f(q0.y);
        acc.z += v0 * bf2f(q0.z); acc.w += v0 * bf2f(q0.w);
    }
    acc.x += acc2.x; acc.y += acc2.y; acc.z += acc2.z; acc.w += acc2.w;

    float4 bi = *(const float4*)(a.bias[si] + sub * 4);
    float4 h;
    h.x = acc.x + bi.x; h.y = acc.y + bi.y; h.z = acc.z + bi.z; h.w = acc.w + bi.w;
    h.x = h.x > 0.f ? h.x : LSLOPE * h.x;
    h.y = h.y > 0.f ? h.y : LSLOPE * h.y;
    h.z = h.z > 0.f ? h.z : LSLOPE * h.z;
    h.w = h.w > 0.f ? h.w : LSLOPE * h.w;
    float4 cu = *(const float4*)(a.cur[si] + (size_t)row * D + sub * 4);
    float4 x;
    x.x = cu.x + h.x; x.y = cu.y + h.y; x.z = cu.z + h.z; x.w = cu.w + h.w;

    float s  = x.x + x.y + x.z + x.w;
    float s2 = x.x * x.x + x.y * x.y + x.z * x.z + x.w * x.w;
    #pragma unroll
    for (int m = 8; m >= 1; m >>= 1) {
        s  += __shfl_xor(s, m, 64);
        s2 += __shfl_xor(s2, m, 64);
    }
    float mean = s * (1.f / 64.f);
    float var  = s2 * (1.f / 64.f) - mean * mean;
    float rstd = rsqrtf(var + LN_EPS);

    float4 g4  = *(const float4*)(a.gamma[si] + sub * 4);
    float4 be4 = *(const float4*)(a.beta[si]  + sub * 4);
    float4 o;
    o.x = (x.x - mean) * rstd * g4.x + be4.x;
    o.y = (x.y - mean) * rstd * g4.y + be4.y;
    o.z = (x.z - mean) * rstd * g4.z + be4.z;
    o.w = (x.w - mean) * rstd * g4.w + be4.w;
    *(float4*)(a.dst[si] + (size_t)row * D + sub * 4) = o;
}

// ---------------------------------------------------------------------------
extern "C" void kernel_launch(void* const* d_in, const int* in_sizes, int n_in,
                              void* d_out, int out_size, void* d_ws, size_t ws_size,
                              hipStream_t stream)
{
    const float* user_emb = (const float*)d_in[0];
    const float* item_emb = (const float*)d_in[1];
    const int*   ui_rows  = (const int*)d_in[2];
    const int*   ui_cols  = (const int*)d_in[3];
    const float* ui_vals  = (const float*)d_in[4];
    const int*   soc_rows = (const int*)d_in[5];
    const int*   soc_cols = (const int*)d_in[6];
    const float* soc_vals = (const float*)d_in[7];
    const float* ui_W     = (const float*)d_in[8];
    const float* ui_b     = (const float*)d_in[9];
    const float* soc_W    = (const float*)d_in[10];
    const float* soc_b    = (const float*)d_in[11];
    const float* ln_ui_g  = (const float*)d_in[12];
    const float* ln_ui_b  = (const float*)d_in[13];
    const float* ln_soc_g = (const float*)d_in[14];
    const float* ln_soc_b = (const float*)d_in[15];

    float* out = (float*)d_out;
    const size_t UD = (size_t)U_N * D;
    const size_t ID = (size_t)I_N * D;

    float* o_ui0 = out;
    float* o_ui1 = out + UD;
    float* o_ui2 = out + 2 * UD;
    float* o_s0  = out + 3 * UD;
    float* o_s1  = out + 4 * UD;
    float* o_s2  = out + 5 * UD;
    float* o_ci  = out + 6 * UD;

    // workspace layout (same ~93 MB footprint as proven in round 3)
    int2* pairs_ui  = (int2*)d_ws;                       // 2M
    int2* pairs_uiT = pairs_ui + NNZ_UI;                 // 2M
    int2* pairs_soc = pairs_uiT + NNZ_UI;                // 1M
    int*  rp_ui     = (int*)(pairs_soc + NNZ_SOC);       // U_N
    int*  rp_uiT    = rp_ui + U_N;                       // I_N
    int*  rp_soc    = rp_uiT + I_N;                      // U_N
    int*  bsum      = rp_soc + U_N;                      // 512
    unsigned short* wbf = (unsigned short*)(bsum + 512); // 16384
    unsigned short* Yi  = wbf + 16384;                   // I*D bf16 (25.6 MB)
    unsigned short* Yu  = Yi + ID;                       // U*D bf16
    unsigned short* Ys  = Yu + UD;                       // U*D bf16
    // bucket copy + count matrices overlap the Y region (dead before T0)
    int2* bkt_ui  = (int2*)Yi;                           // 2M int2
    int2* bkt_uiT = bkt_ui + NNZ_UI;                     // 2M
    int2* bkt_soc = bkt_uiT + NNZ_UI;                    // 1M
    int*  cnt_ui  = (int*)(bkt_soc + NNZ_SOC);           // NB_UI*NBLK_UI
    int*  cnt_uiT = cnt_ui + NB_UI * NBLK_UI;            // NB_UIT*NBLK_UI
    int*  cnt_soc = cnt_uiT + NB_UIT * NBLK_UI;          // NB_SOC*NBLK_SOC

    const unsigned short* wbfUI0 = wbf;
    const unsigned short* wbfUI1 = wbf + 4096;
    const unsigned short* wbfS0  = wbf + 8192;
    const unsigned short* wbfS1  = wbf + 12288;

    const int nthr = 256;

    // 1) weights to bf16
    wbf_k<<<64, nthr, 0, stream>>>(ui_W, soc_W, wbf);

    // 2) Phase A: bucket counts (no global atomics)
    {
        BCArgs ba;
        ba.rows4[0] = (const int4*)ui_rows;  ba.cnt[0] = cnt_ui;  ba.nnz[0] = NNZ_UI;
        ba.nblk[0] = NBLK_UI;  ba.nbuck[0] = NB_UI;
        ba.rows4[1] = (const int4*)ui_cols;  ba.cnt[1] = cnt_uiT; ba.nnz[1] = NNZ_UI;
        ba.nblk[1] = NBLK_UI;  ba.nbuck[1] = NB_UIT;
        ba.rows4[2] = (const int4*)soc_rows; ba.cnt[2] = cnt_soc; ba.nnz[2] = NNZ_SOC;
        ba.nblk[2] = NBLK_SOC; ba.nbuck[2] = NB_SOC;
        ba.base[0] = 0; ba.base[1] = NBLK_UI; ba.base[2] = 2 * NBLK_UI;
        ba.base[3] = 2 * NBLK_UI + NBLK_SOC;
        bucket_cnt<<<ba.base[3], nthr, 0, stream>>>(ba);
    }

    // 3) Phase B: exclusive scans over the bucket-major count matrices
    {
        ScanArgs sa;
        sa.cnt[0] = cnt_ui;  sa.n[0] = NB_UI * NBLK_UI;     // 125440
        sa.cnt[1] = cnt_uiT; sa.n[1] = NB_UIT * NBLK_UI;    // 250880
        sa.cnt[2] = cnt_soc; sa.n[2] = NB_SOC * NBLK_SOC;   // 62976
        int nb0 = (sa.n[0] + SCAN_CHUNK - 1) / SCAN_CHUNK;  // 123
        int nb1 = (sa.n[1] + SCAN_CHUNK - 1) / SCAN_CHUNK;  // 245
        int nb2 = (sa.n[2] + SCAN_CHUNK - 1) / SCAN_CHUNK;  // 62
        sa.nb[0] = nb0; sa.nb[1] = nb1; sa.nb[2] = nb2;
        sa.off[0] = 0; sa.off[1] = nb0; sa.off[2] = nb0 + nb1;
        sa.base[0] = 0; sa.base[1] = nb0; sa.base[2] = nb0 + nb1; sa.base[3] = nb0 + nb1 + nb2;
        scan_p1<<<sa.base[3], nthr, 0, stream>>>(sa, bsum);
        scan_p2<<<3, nthr, 0, stream>>>(sa, bsum);
        scan_p3<<<sa.base[3], nthr, 0, stream>>>(sa, bsum);
    }

    // 4) Phase C: bucket-grouped edge copy (LDS-rank positions)
    {
        BSArgs ca;
        ca.rows[0] = ui_rows;  ca.cols[0] = ui_cols;  ca.vals[0] = ui_vals;
        ca.cofs[0] = cnt_ui;  ca.bkt[0] = bkt_ui;  ca.nnz[0] = NNZ_UI;
        ca.nblk[0] = NBLK_UI;  ca.nbuck[0] = NB_UI;
        ca.rows[1] = ui_cols;  ca.cols[1] = ui_rows;  ca.vals[1] = ui_vals;
        ca.cofs[1] = cnt_uiT; ca.bkt[1] = bkt_uiT; ca.nnz[1] = NNZ_UI;
        ca.nblk[1] = NBLK_UI;  ca.nbuck[1] = NB_UIT;
        ca.rows[2] = soc_rows; ca.cols[2] = soc_cols; ca.vals[2] = soc_vals;
        ca.cofs[2] = cnt_soc; ca.bkt[2] = bkt_soc; ca.nnz[2] = NNZ_SOC;
        ca.nblk[2] = NBLK_SOC; ca.nbuck[2] = NB_SOC;
        ca.base[0] = 0; ca.base[1] = NBLK_UI; ca.base[2] = 2 * NBLK_UI;
        ca.base[3] = 2 * NBLK_UI + NBLK_SOC;
        bucket_scat<<<ca.base[3], nthr, 0, stream>>>(ca);
    }

    // 5) copy user_emb to output slots (overlaps with CSR build)
    copy2_f4<<<(int)(UD / 4 + nthr - 1) / nthr, nthr, 0, stream>>>(
        (const float4*)user_emb, (float4*)o_ui0, (float4*)o_s0, (int)(UD / 4));

    // 6) Phase D: per-bucket CSR finalize (rp + row-sorted pairs), LDS only
    {
        BDArgs da;
        da.cofs[0] = cnt_ui;  da.bkt[0] = bkt_ui;  da.pairs[0] = pairs_ui;  da.rp[0] = rp_ui;
        da.nnz[0] = NNZ_UI;  da.nblk[0] = NBLK_UI;  da.nbuck[0] = NB_UI;  da.nrows[0] = U_N;
        da.cofs[1] = cnt_uiT; da.bkt[1] = bkt_uiT; da.pairs[1] = pairs_uiT; da.rp[1] = rp_uiT;
        da.nnz[1] = NNZ_UI;  da.nblk[1] = NBLK_UI;  da.nbuck[1] = NB_UIT; da.nrows[1] = I_N;
        da.cofs[2] = cnt_soc; da.bkt[2] = bkt_soc; da.pairs[2] = pairs_soc; da.rp[2] = rp_soc;
        da.nnz[2] = NNZ_SOC; da.nblk[2] = NBLK_SOC; da.nbuck[2] = NB_SOC;  da.nrows[2] = U_N;
        da.base[0] = 0; da.base[1] = NB_UI; da.base[2] = NB_UI + NB_UIT;
        da.base[3] = NB_UI + NB_UIT + NB_SOC;
        bucket_csr<<<da.base[3], nthr, 0, stream>>>(da);
    }

    const int xb_i = (I_N + 63) / 64;
    const int xb_u = (U_N + 63) / 64;

    // 7) T0 (overwrites bkt/cnt region — only after bucket_csr)
    {
        XfArgs xa;
        xa.src[0] = item_emb; xa.wbf[0] = wbfUI0; xa.dst[0] = Yi; xa.n[0] = I_N;
        xa.src[1] = user_emb; xa.wbf[1] = wbfUI0; xa.dst[1] = Yu; xa.n[1] = U_N;
        xa.src[2] = user_emb; xa.wbf[2] = wbfS0;  xa.dst[2] = Ys; xa.n[2] = U_N;
        xa.base[0] = 0; xa.base[1] = xb_i; xa.base[2] = xb_i + xb_u; xa.base[3] = xb_i + 2 * xb_u;
        xform_mfma<<<xa.base[3], nthr, 0, stream>>>(xa);
    }

    // 8) spmm L0
    {
        SpArgs pa;
        pa.rptr[0] = rp_ui;  pa.pairs[0] = pairs_ui;  pa.y[0] = Yi; pa.cur[0] = user_emb;
        pa.bias[0] = ui_b;  pa.gamma[0] = ln_ui_g;  pa.beta[0] = ln_ui_b;  pa.dst[0] = o_ui1;
        pa.n[0] = U_N; pa.nnzc[0] = NNZ_UI;
        pa.rptr[1] = rp_uiT; pa.pairs[1] = pairs_uiT; pa.y[1] = Yu; pa.cur[1] = item_emb;
        pa.bias[1] = ui_b;  pa.gamma[1] = ln_ui_g;  pa.beta[1] = ln_ui_b;  pa.dst[1] = o_ci;
        pa.n[1] = I_N; pa.nnzc[1] = NNZ_UI;
        pa.rptr[2] = rp_soc; pa.pairs[2] = pairs_soc; pa.y[2] = Ys; pa.cur[2] = user_emb;
        pa.bias[2] = soc_b; pa.gamma[2] = ln_soc_g; pa.beta[2] = ln_soc_b; pa.dst[2] = o_s1;
        pa.n[2] = U_N; pa.nnzc[2] = NNZ_SOC;
        pa.base[0] = 0; pa.base[1] = U_N / 16; pa.base[2] = U_N / 16 + I_N / 16;
        pa.base[3] = 2 * (U_N / 16) + I_N / 16;
        spmm_ln<<<pa.base[3], nthr, 0, stream>>>(pa);
    }

    // 9) T1
    {
        XfArgs xa;
        xa.src[0] = o_ci;  xa.wbf[0] = wbfUI1; xa.dst[0] = Yi; xa.n[0] = I_N;
        xa.src[1] = o_ui1; xa.wbf[1] = wbfUI1; xa.dst[1] = Yu; xa.n[1] = U_N;
        xa.src[2] = o_s1;  xa.wbf[2] = wbfS1;  xa.dst[2] = Ys; xa.n[2] = U_N;
        xa.base[0] = 0; xa.base[1] = xb_i; xa.base[2] = xb_i + xb_u; xa.base[3] = xb_i + 2 * xb_u;
        xform_mfma<<<xa.base[3], nthr, 0, stream>>>(xa);
    }

    // 10) spmm L1
    {
        SpArgs pa;
        pa.rptr[0] = rp_ui;  pa.pairs[0] = pairs_ui;  pa.y[0] = Yi; pa.cur[0] = o_ui1;
        pa.bias[0] = ui_b + 64;  pa.gamma[0] = ln_ui_g + 64;  pa.beta[0] = ln_ui_b + 64;
        pa.dst[0] = o_ui2;
        pa.n[0] = U_N; pa.nnzc[0] = NNZ_UI;
        pa.rptr[1] = rp_uiT; pa.pairs[1] = pairs_uiT; pa.y[1] = Yu; pa.cur[1] = o_ci;
        pa.bias[1] = ui_b + 64;  pa.gamma[1] = ln_ui_g + 64;  pa.beta[1] = ln_ui_b + 64;
        pa.dst[1] = o_ci;   // in-place: row read then written by same thread
        pa.n[1] = I_N; pa.nnzc[1] = NNZ_UI;
        pa.rptr[2] = rp_soc; pa.pairs[2] = pairs_soc; pa.y[2] = Ys; pa.cur[2] = o_s1;
        pa.bias[2] = soc_b + 64; pa.gamma[2] = ln_soc_g + 64; pa.beta[2] = ln_soc_b + 64;
        pa.dst[2] = o_s2;
        pa.n[2] = U_N; pa.nnzc[2] = NNZ_SOC;
        pa.base[0] = 0; pa.base[1] = U_N / 16; pa.base[2] = U_N / 16 + I_N / 16;
        pa.base[3] = 2 * (U_N / 16) + I_N / 16;
        spmm_ln<<<pa.base[3], nthr, 0, stream>>>(pa);
    }
}